// Round 1
// baseline (161.401 us; speedup 1.0000x reference)
//
#include <hip/hip_runtime.h>

#define NS 1048576
#define NFLOW 8
#define HD 64
#define GT 8192

// ---------- helpers ----------
__device__ __forceinline__ unsigned fenc(float f) {
    unsigned u = __float_as_uint(f);
    return (u & 0x80000000u) ? ~u : (u | 0x80000000u);
}
__device__ __forceinline__ float fdec(unsigned e) {
    unsigned u = (e & 0x80000000u) ? (e & 0x7fffffffu) : ~e;
    return __uint_as_float(u);
}

// ws layout:
//   [0..7]   double S accumulator
//   [8..15]  unsigned min_enc, max_enc  (of eps[:,0])
//   [16..63] float params: bm0,bm1,bm2, Lc00,Lc10,Lc11,Lc20,Lc21,Lc22
//   [64 .. 64+GT*16)            float4 tabAB[GT]   (A1,B1,A2,B2)
//   [64+GT*16 .. 64+GT*16+GT*4) float  tabLD[GT]
__device__ __forceinline__ void grid_params(const char* ws, float& gmin, float& ginv, float& gdel) {
    const unsigned* mm = (const unsigned*)(ws + 8);
    const float* pr = (const float*)(ws + 16);
    float emin = fdec(mm[0]), emax = fdec(mm[1]);
    float bm0 = pr[0], Lc00 = pr[3];  // Lc00 > 0 by Cholesky construction
    float z0a = fmaf(Lc00, emin, bm0);
    float z0b = fmaf(Lc00, emax, bm0);
    float pad = (z0b - z0a) * 1e-4f + 1e-6f;
    gmin = z0a - pad;
    float gmax = z0b + pad;
    gdel = (gmax - gmin) * (1.0f / (GT - 1));
    ginv = (float)(GT - 1) / (gmax - gmin);
}

// ---------- kernel 0: init ws header + 3x3 Cholesky (fp64) ----------
__global__ void k_init(const float* __restrict__ L_tril, const float* __restrict__ base_mean,
                       char* __restrict__ ws) {
    double* S = (double*)ws;
    unsigned* mm = (unsigned*)(ws + 8);
    float* pr = (float*)(ws + 16);
    *S = 0.0;
    mm[0] = 0xFFFFFFFFu;  // running min (encoded)
    mm[1] = 0u;           // running max (encoded)
    double l00 = (double)L_tril[0] + 1e-6;
    double l10 = (double)L_tril[3];
    double l11 = (double)L_tril[4] + 1e-6;
    double l20 = (double)L_tril[6];
    double l21 = (double)L_tril[7];
    double l22 = (double)L_tril[8] + 1e-6;
    double c00 = l00 * l00;
    double c10 = l10 * l00;
    double c11 = l10 * l10 + l11 * l11;
    double c20 = l20 * l00;
    double c21 = l20 * l10 + l21 * l11;
    double c22 = l20 * l20 + l21 * l21 + l22 * l22;
    double d00 = sqrt(c00);
    double d10 = c10 / d00;
    double d20 = c20 / d00;
    double d11 = sqrt(c11 - d10 * d10);
    double d21 = (c21 - d20 * d10) / d11;
    double d22 = sqrt(c22 - d20 * d20 - d21 * d21);
    pr[0] = base_mean[0]; pr[1] = base_mean[1]; pr[2] = base_mean[2];
    pr[3] = (float)d00; pr[4] = (float)d10; pr[5] = (float)d11;
    pr[6] = (float)d20; pr[7] = (float)d21; pr[8] = (float)d22;
}

// ---------- kernel 1: min/max of eps[:,0] ----------
__global__ void __launch_bounds__(256) k_minmax(const float4* __restrict__ eps4, char* __restrict__ ws) {
    int i = blockIdx.x * blockDim.x + threadIdx.x;
    float4 a = eps4[3 * i], b = eps4[3 * i + 1], c = eps4[3 * i + 2];
    float mn = fminf(fminf(a.x, a.w), fminf(b.z, c.y));
    float mx = fmaxf(fmaxf(a.x, a.w), fmaxf(b.z, c.y));
    for (int o = 32; o > 0; o >>= 1) {
        mn = fminf(mn, __shfl_down(mn, o));
        mx = fmaxf(mx, __shfl_down(mx, o));
    }
    __shared__ float smn[4], smx[4];
    int lane = threadIdx.x & 63, wid = threadIdx.x >> 6;
    if (lane == 0) { smn[wid] = mn; smx[wid] = mx; }
    __syncthreads();
    if (threadIdx.x == 0) {
        mn = fminf(fminf(smn[0], smn[1]), fminf(smn[2], smn[3]));
        mx = fmaxf(fmaxf(smx[0], smx[1]), fmaxf(smx[2], smx[3]));
        unsigned* mm = (unsigned*)(ws + 8);
        atomicMin(&mm[0], fenc(mn));
        atomicMax(&mm[1], fenc(mx));
    }
}

// ---------- kernel 2: per-(gridpoint, flow) MLP -> (s0, s1, sh0, sh1) ----------
__global__ void __launch_bounds__(256) k_table(
    const float* __restrict__ W1, const float* __restrict__ b1,
    const float* __restrict__ W2, const float* __restrict__ b2,
    const float* __restrict__ W3, const float* __restrict__ b3,
    const char* __restrict__ ws, float4* __restrict__ partial) {
    int p = blockIdx.x * blockDim.x + threadIdx.x;
    int t = blockIdx.y;
    float gmin, ginv, gdel;
    grid_params(ws, gmin, ginv, gdel);
    (void)ginv;
    float z0 = fmaf(gdel, (float)p, gmin);
    const float* w1 = W1 + t * HD;        // (HD,1)
    const float* bb1 = b1 + t * HD;
    const float* w2 = W2 + t * HD * HD;   // (HD,HD)
    const float* bb2 = b2 + t * HD;
    const float* w3 = W3 + t * 4 * HD;    // (4,HD)
    const float* bb3 = b3 + t * 4;
    float h1[HD];
#pragma unroll
    for (int k = 0; k < HD; k++) {
        float v = fmaf(z0, w1[k], bb1[k]);
        h1[k] = v > 0.f ? v : 0.f;
    }
    float p0 = bb3[0], p1 = bb3[1], p2 = bb3[2], p3 = bb3[3];
    for (int j = 0; j < HD; j++) {
        const float* r = w2 + j * HD;
        float acc = bb2[j];
#pragma unroll
        for (int k = 0; k < HD; k++) acc = fmaf(r[k], h1[k], acc);
        float h = acc > 0.f ? acc : 0.f;
        p0 = fmaf(w3[j], h, p0);
        p1 = fmaf(w3[HD + j], h, p1);
        p2 = fmaf(w3[2 * HD + j], h, p2);
        p3 = fmaf(w3[3 * HD + j], h, p3);
    }
    partial[t * GT + p] = make_float4(tanhf(p0), tanhf(p1), p2, p3);
}

// ---------- kernel 3: compose 8 flows per grid point ----------
__global__ void __launch_bounds__(256) k_compose(const float4* __restrict__ partial, char* __restrict__ ws) {
    int p = blockIdx.x * blockDim.x + threadIdx.x;
    float A1 = 1.f, B1 = 0.f, A2 = 1.f, B2 = 0.f, LD = 0.f;
#pragma unroll
    for (int t = 0; t < NFLOW; t++) {
        float4 v = partial[t * GT + p];
        float a1 = expf(v.x), a2 = expf(v.y);
        A1 *= a1; B1 = fmaf(B1, a1, v.z);
        A2 *= a2; B2 = fmaf(B2, a2, v.w);
        LD += v.x + v.y;
    }
    float4* tabAB = (float4*)(ws + 64);
    float* tabLD = (float*)(ws + 64 + GT * 16);
    tabAB[p] = make_float4(A1, B1, A2, B2);
    tabLD[p] = LD;
}

// ---------- kernel 4: main per-sample pass ----------
__global__ void __launch_bounds__(256) k_main(const float4* __restrict__ eps4, char* __restrict__ ws,
                                              float* __restrict__ out) {
    int i = blockIdx.x * blockDim.x + threadIdx.x;
    const float* pr = (const float*)(ws + 16);
    float bm0 = pr[0], bm1 = pr[1], bm2 = pr[2];
    float Lc00 = pr[3], Lc10 = pr[4], Lc11 = pr[5], Lc20 = pr[6], Lc21 = pr[7], Lc22 = pr[8];
    float gmin, ginv, gdel;
    grid_params(ws, gmin, ginv, gdel);
    (void)gdel;
    const float4* tabAB = (const float4*)(ws + 64);
    const float* tabLD = (const float*)(ws + 64 + GT * 16);
    float4 a = eps4[3 * i], b = eps4[3 * i + 1], c = eps4[3 * i + 2];
    float e0[4] = {a.x, a.w, b.z, c.y};
    float e1[4] = {a.y, b.x, b.w, c.z};
    float e2[4] = {a.z, b.y, c.x, c.w};
    float zo[12], ld[4];
    float lsum = 0.f;
#pragma unroll
    for (int s = 0; s < 4; s++) {
        float z0 = fmaf(Lc00, e0[s], bm0);
        float z1 = fmaf(Lc11, e1[s], fmaf(Lc10, e0[s], bm1));
        float z2 = fmaf(Lc22, e2[s], fmaf(Lc21, e1[s], fmaf(Lc20, e0[s], bm2)));
        float u = (z0 - gmin) * ginv;
        u = fminf(fmaxf(u, 0.f), (float)(GT - 1));
        int g = (int)u;
        if (g > GT - 2) g = GT - 2;
        float f = u - (float)g;
        float4 t0 = tabAB[g], t1 = tabAB[g + 1];
        float A1 = fmaf(f, t1.x - t0.x, t0.x);
        float B1 = fmaf(f, t1.y - t0.y, t0.y);
        float A2 = fmaf(f, t1.z - t0.z, t0.z);
        float B2 = fmaf(f, t1.w - t0.w, t0.w);
        float l0 = tabLD[g];
        float LD = fmaf(f, tabLD[g + 1] - l0, l0);
        float z1f = fmaf(z1, A1, B1);
        float z2f = fmaf(z2, A2, B2);
        zo[3 * s] = z0;
        zo[3 * s + 1] = expf(z1f);
        zo[3 * s + 2] = expf(z2f);
        ld[s] = LD;
        lsum += z1f + z2f;
    }
    float4* o4 = (float4*)out;
    o4[3 * i]     = make_float4(zo[0], zo[1], zo[2], zo[3]);
    o4[3 * i + 1] = make_float4(zo[4], zo[5], zo[6], zo[7]);
    o4[3 * i + 2] = make_float4(zo[8], zo[9], zo[10], zo[11]);
    ((float4*)(out + 3 * (size_t)NS))[i] = make_float4(ld[0], ld[1], ld[2], ld[3]);
    // global sum of z1f+z2f
    for (int o = 32; o > 0; o >>= 1) lsum += __shfl_down(lsum, o);
    __shared__ float sred[4];
    int lane = threadIdx.x & 63, wid = threadIdx.x >> 6;
    if (lane == 0) sred[wid] = lsum;
    __syncthreads();
    if (threadIdx.x == 0) {
        double tot = (double)sred[0] + (double)sred[1] + (double)sred[2] + (double)sred[3];
        atomicAdd((double*)ws, tot);
    }
}

// ---------- kernel 5: broadcast-add S to log_det ----------
__global__ void __launch_bounds__(256) k_adds(float* __restrict__ out, const char* __restrict__ ws) {
    int i = blockIdx.x * blockDim.x + threadIdx.x;
    float S = (float)(*(const double*)ws);
    float4* p = (float4*)(out + 3 * (size_t)NS);
    float4 v = p[i];
    v.x += S; v.y += S; v.z += S; v.w += S;
    p[i] = v;
}

extern "C" void kernel_launch(void* const* d_in, const int* in_sizes, int n_in,
                              void* d_out, int out_size, void* d_ws, size_t ws_size,
                              hipStream_t stream) {
    const float* L_tril = (const float*)d_in[0];
    const float* bm     = (const float*)d_in[1];
    const float* W1     = (const float*)d_in[2];
    const float* b1     = (const float*)d_in[3];
    const float* W2     = (const float*)d_in[4];
    const float* b2     = (const float*)d_in[5];
    const float* W3     = (const float*)d_in[6];
    const float* b3     = (const float*)d_in[7];
    const float* eps    = (const float*)d_in[8];
    char* ws = (char*)d_ws;
    float* out = (float*)d_out;

    k_init<<<1, 1, 0, stream>>>(L_tril, bm, ws);
    k_minmax<<<NS / 4 / 256, 256, 0, stream>>>((const float4*)eps, ws);
    // partial table staged in d_out (1 MB; overwritten later by k_main)
    k_table<<<dim3(GT / 256, NFLOW), 256, 0, stream>>>(W1, b1, W2, b2, W3, b3, ws, (float4*)d_out);
    k_compose<<<GT / 256, 256, 0, stream>>>((const float4*)d_out, ws);
    k_main<<<NS / 4 / 256, 256, 0, stream>>>((const float4*)eps, ws, out);
    k_adds<<<NS / 4 / 256, 256, 0, stream>>>(out, ws);
}